// Round 1
// baseline (7502.908 us; speedup 1.0000x reference)
//
#include <hip/hip_runtime.h>

#define SEQ   256
#define DIN   8192
#define BATCH 2048
#define HID   512
#define G4    2048   // 4*HID
#define KG    544    // HID + 32

typedef __attribute__((ext_vector_type(8))) short short8;
typedef __attribute__((ext_vector_type(4))) float f32x4;

static __device__ __forceinline__ unsigned short f2bf(float f) {
  unsigned int u = __float_as_uint(f);
  return (unsigned short)((u + 0x7FFFu + ((u >> 16) & 1u)) >> 16);
}
static __device__ __forceinline__ float bf2f(unsigned short u) {
  return __uint_as_float(((unsigned int)u) << 16);
}
static __device__ __forceinline__ float sigmoidf_(float x) {
  return 1.f / (1.f + __expf(-x));
}
static __device__ __forceinline__ float tanhf_(float x) {
  // stable: 1 - 2/(e^{2x}+1); saturates correctly for |x| large
  return 1.f - 2.f / (__expf(2.f * x) + 1.f);
}

// ---------------- BatchNorm stats (two-stage) ----------------
__global__ __launch_bounds__(256) void bn_partial(const float* __restrict__ x,
                                                  float* __restrict__ psum,
                                                  float* __restrict__ psq) {
  int c = blockIdx.x * 256 + threadIdx.x;       // 0..8191
  int r0 = blockIdx.y * 256;
  float s = 0.f, q = 0.f;
#pragma unroll 8
  for (int r = r0; r < r0 + 256; ++r) {
    float v = x[(size_t)r * DIN + c];
    s += v; q += v * v;
  }
  psum[blockIdx.y * DIN + c] = s;
  psq[blockIdx.y * DIN + c] = q;
}

__global__ __launch_bounds__(256) void bn_finalize(const float* __restrict__ psum,
                                                   const float* __restrict__ psq,
                                                   const float* __restrict__ gamma,
                                                   const float* __restrict__ beta,
                                                   float* __restrict__ scale,
                                                   float* __restrict__ shift) {
  int c = blockIdx.x * 256 + threadIdx.x;
  float s = 0.f, q = 0.f;
#pragma unroll
  for (int i = 0; i < 8; ++i) { s += psum[i * DIN + c]; q += psq[i * DIN + c]; }
  float mean = s * (1.f / BATCH);
  float var = q * (1.f / BATCH) - mean * mean;
  float sc = gamma[c] * rsqrtf(var + 1e-5f);
  scale[c] = sc;
  shift[c] = beta[c] - mean * sc;
}

// ---------------- prep: conversions ----------------
__global__ __launch_bounds__(256) void cvt_bf16(const float* __restrict__ in,
                                                unsigned short* __restrict__ out, long n) {
  long i = ((long)blockIdx.x * 256 + threadIdx.x) * 8;
  if (i >= n) return;
  float4 a = *(const float4*)(in + i);
  float4 b = *(const float4*)(in + i + 4);
  ushort4 lo, hi;
  lo.x = f2bf(a.x); lo.y = f2bf(a.y); lo.z = f2bf(a.z); lo.w = f2bf(a.w);
  hi.x = f2bf(b.x); hi.y = f2bf(b.y); hi.z = f2bf(b.z); hi.w = f2bf(b.w);
  *(ushort4*)(out + i) = lo;
  *(ushort4*)(out + i + 4) = hi;
}

// Wg[g][k] : k<512 -> W_hh[g][k] ; k>=512 -> W_ih[g][k-512].  bias = b_ih+b_hh
__global__ __launch_bounds__(256) void build_wg(const float* __restrict__ W_hh,
                                                const float* __restrict__ W_ih,
                                                const float* __restrict__ b_ih,
                                                const float* __restrict__ b_hh,
                                                unsigned short* __restrict__ Wg,
                                                float* __restrict__ bias) {
  int g = blockIdx.x;
  for (int k = threadIdx.x; k < KG; k += 256) {
    float v = (k < HID) ? W_hh[(size_t)g * HID + k] : W_ih[(size_t)g * 32 + (k - HID)];
    Wg[(size_t)g * KG + k] = f2bf(v);
  }
  if (threadIdx.x == 0) bias[g] = b_ih[g] + b_hh[g];
}

// ---------------- GEMM1: C = norm(x) @ W_in^T + b_in  -> xs bf16 [T][B][32] ----------------
template<int BF16B>
__global__ __launch_bounds__(256) void gemm1(const float* __restrict__ x,
                                             const float* __restrict__ scale,
                                             const float* __restrict__ shift,
                                             const void* __restrict__ Bsrc,
                                             const float* __restrict__ b_in,
                                             unsigned short* __restrict__ xs) {
  __shared__ unsigned short As[128 * 40];
  __shared__ unsigned short Bs[128 * 40];
  const int tid = threadIdx.x;
  const int lane = tid & 63;
  const int wave = tid >> 6;
  const int wm = (wave >> 1) * 64, wn = (wave & 1) * 64;
  const int bn = blockIdx.x * 128, bm = blockIdx.y * 128;
  const int lr = lane & 15;
  const int kq = (lane >> 4) * 8;

  f32x4 acc[4][4] = {};

  for (int k0 = 0; k0 < DIN; k0 += 32) {
    // stage A: 128x32 f32 -> normalized bf16
#pragma unroll
    for (int i = 0; i < 4; ++i) {
      int idx = tid + i * 256;
      int row = idx >> 3, c4 = (idx & 7) * 4;
      float4 v = *(const float4*)&x[(size_t)(bm + row) * DIN + k0 + c4];
      float4 sc = *(const float4*)&scale[k0 + c4];
      float4 sh = *(const float4*)&shift[k0 + c4];
      ushort4 o;
      o.x = f2bf(v.x * sc.x + sh.x);
      o.y = f2bf(v.y * sc.y + sh.y);
      o.z = f2bf(v.z * sc.z + sh.z);
      o.w = f2bf(v.w * sc.w + sh.w);
      *(ushort4*)&As[row * 40 + c4] = o;
    }
    // stage B
    if constexpr (BF16B) {
      const unsigned short* W = (const unsigned short*)Bsrc;
#pragma unroll
      for (int i = 0; i < 2; ++i) {
        int idx = tid + i * 256;
        int row = idx >> 2, cc = (idx & 3) * 8;
        *(int4*)&Bs[row * 40 + cc] = *(const int4*)&W[(size_t)(bn + row) * DIN + k0 + cc];
      }
    } else {
      const float* W = (const float*)Bsrc;
#pragma unroll
      for (int i = 0; i < 4; ++i) {
        int idx = tid + i * 256;
        int row = idx >> 3, c4 = (idx & 7) * 4;
        float4 v = *(const float4*)&W[(size_t)(bn + row) * DIN + k0 + c4];
        ushort4 o;
        o.x = f2bf(v.x); o.y = f2bf(v.y); o.z = f2bf(v.z); o.w = f2bf(v.w);
        *(ushort4*)&Bs[row * 40 + c4] = o;
      }
    }
    __syncthreads();
    short8 af[4], bfr[4];
#pragma unroll
    for (int i = 0; i < 4; ++i) af[i] = *(const short8*)&As[(wm + i * 16 + lr) * 40 + kq];
#pragma unroll
    for (int j = 0; j < 4; ++j) bfr[j] = *(const short8*)&Bs[(wn + j * 16 + lr) * 40 + kq];
#pragma unroll
    for (int i = 0; i < 4; ++i)
#pragma unroll
      for (int j = 0; j < 4; ++j)
        acc[i][j] = __builtin_amdgcn_mfma_f32_16x16x32_bf16(af[i], bfr[j], acc[i][j], 0, 0, 0);
    __syncthreads();
  }
  // epilogue: +b_in, write xs[t][b][d] with t=col>>5, d=col&31
#pragma unroll
  for (int i = 0; i < 4; ++i)
#pragma unroll
    for (int j = 0; j < 4; ++j)
#pragma unroll
      for (int r = 0; r < 4; ++r) {
        int row = bm + wm + i * 16 + (lane >> 4) * 4 + r;
        int col = bn + wn + j * 16 + lr;
        float val = acc[i][j][r] + b_in[col];
        xs[((size_t)(col >> 5) * BATCH + row) * 32 + (col & 31)] = f2bf(val);
      }
}

// ---------------- per-step GEMM: gates = [h | xs_t] @ Wg^T + bias ----------------
__global__ __launch_bounds__(256) void step_gemm(const unsigned short* __restrict__ h,
                                                 const unsigned short* __restrict__ xst,
                                                 const unsigned short* __restrict__ Wg,
                                                 const float* __restrict__ bias,
                                                 float* __restrict__ gates) {
  __shared__ unsigned short As[128 * 40];
  __shared__ unsigned short Bs[128 * 40];
  const int tid = threadIdx.x;
  const int lane = tid & 63;
  const int wave = tid >> 6;
  const int wm = (wave >> 1) * 64, wn = (wave & 1) * 64;
  const int bn = blockIdx.x * 128, bm = blockIdx.y * 128;
  const int lr = lane & 15;
  const int kq = (lane >> 4) * 8;

  f32x4 acc[4][4] = {};

  for (int kt = 0; kt < 17; ++kt) {
    const int k0 = kt * 32;
#pragma unroll
    for (int i = 0; i < 2; ++i) {
      int idx = tid + i * 256;
      int row = idx >> 2, cc = (idx & 3) * 8;
      int4 v;
      if (k0 < HID) v = *(const int4*)&h[(size_t)(bm + row) * HID + k0 + cc];
      else          v = *(const int4*)&xst[(size_t)(bm + row) * 32 + cc];
      *(int4*)&As[row * 40 + cc] = v;
      *(int4*)&Bs[row * 40 + cc] = *(const int4*)&Wg[(size_t)(bn + row) * KG + k0 + cc];
    }
    __syncthreads();
    short8 af[4], bfr[4];
#pragma unroll
    for (int i = 0; i < 4; ++i) af[i] = *(const short8*)&As[(wm + i * 16 + lr) * 40 + kq];
#pragma unroll
    for (int j = 0; j < 4; ++j) bfr[j] = *(const short8*)&Bs[(wn + j * 16 + lr) * 40 + kq];
#pragma unroll
    for (int i = 0; i < 4; ++i)
#pragma unroll
      for (int j = 0; j < 4; ++j)
        acc[i][j] = __builtin_amdgcn_mfma_f32_16x16x32_bf16(af[i], bfr[j], acc[i][j], 0, 0, 0);
    __syncthreads();
  }
#pragma unroll
  for (int i = 0; i < 4; ++i)
#pragma unroll
    for (int j = 0; j < 4; ++j)
#pragma unroll
      for (int r = 0; r < 4; ++r) {
        int row = bm + wm + i * 16 + (lane >> 4) * 4 + r;
        int col = bn + wn + j * 16 + lr;
        gates[(size_t)row * G4 + col] = acc[i][j][r] + bias[col];
      }
}

// ---------------- LSTM cell elementwise ----------------
__global__ __launch_bounds__(256) void lstm_elt(const float* __restrict__ gates,
                                                float* __restrict__ c,
                                                unsigned short* __restrict__ h) {
  int idx = blockIdx.x * 256 + threadIdx.x;   // 0 .. 2048*512-1
  int b = idx >> 9, u = idx & 511;
  const float* g = gates + (size_t)b * G4;
  float i = sigmoidf_(g[u]);
  float f = sigmoidf_(g[u + 512]);
  float gv = tanhf_(g[u + 1024]);
  float o = sigmoidf_(g[u + 1536]);
  float cn = f * c[idx] + i * gv;
  c[idx] = cn;
  h[idx] = f2bf(o * tanhf_(cn));
}

// ---------------- final GEMV: out[b] = h[b,:] . W_out ----------------
__global__ __launch_bounds__(64) void gemv_out(const unsigned short* __restrict__ h,
                                               const float* __restrict__ Wout,
                                               float* __restrict__ out) {
  int b = blockIdx.x;
  int lane = threadIdx.x;
  float s = 0.f;
#pragma unroll
  for (int i = 0; i < 8; ++i) {
    int u = lane + i * 64;
    s += bf2f(h[(size_t)b * HID + u]) * Wout[u];
  }
#pragma unroll
  for (int off = 32; off > 0; off >>= 1) s += __shfl_down(s, off);
  if (lane == 0) out[b] = s;
}

// ---------------- host ----------------
extern "C" void kernel_launch(void* const* d_in, const int* in_sizes, int n_in,
                              void* d_out, int out_size, void* d_ws, size_t ws_size,
                              hipStream_t stream) {
  const float* x     = (const float*)d_in[0];
  const float* gamma = (const float*)d_in[1];
  const float* beta  = (const float*)d_in[2];
  const float* W_in  = (const float*)d_in[3];
  const float* b_in  = (const float*)d_in[4];
  const float* W_ih  = (const float*)d_in[5];
  const float* W_hh  = (const float*)d_in[6];
  const float* b_ih  = (const float*)d_in[7];
  const float* b_hh  = (const float*)d_in[8];
  const float* W_out = (const float*)d_in[9];
  float* out = (float*)d_out;

  // workspace layout (bytes):
  //   0        scale[8192] f32
  //   32768    shift[8192] f32
  //   65536    bias[2048]  f32
  //   73728    Wg bf16 [2048][544]          (2,228,224 B)
  //   2301952  h   bf16 [2048][512]         (2,097,152 B)
  //   4399104  c   f32  [2048][512]         (4,194,304 B)
  //   8593408  xs  bf16 [256][2048][32]     (33,554,432 B)
  //   42147840 gates f32 [2048][2048]       (16,777,216 B)  (also BN-partials scratch)
  //   58925056 Win bf16 [8192][8192]        (134,217,728 B) — optional
  char* ws = (char*)d_ws;
  float* scale = (float*)(ws + 0);
  float* shift = (float*)(ws + 32768);
  float* bias  = (float*)(ws + 65536);
  unsigned short* Wg   = (unsigned short*)(ws + 73728);
  unsigned short* hbuf = (unsigned short*)(ws + 2301952);
  float* cbuf  = (float*)(ws + 4399104);
  unsigned short* xs   = (unsigned short*)(ws + 8593408);
  float* gates = (float*)(ws + 42147840);
  unsigned short* WinB = (unsigned short*)(ws + 58925056);
  const bool useWinB = ws_size >= (58925056ull + 134217728ull);

  float* psum = gates;            // BN partials live in the gates area (free until steps)
  float* psq  = gates + 8 * DIN;

  hipMemsetAsync(hbuf, 0, (size_t)BATCH * HID * 2, stream);
  hipMemsetAsync(cbuf, 0, (size_t)BATCH * HID * 4, stream);

  bn_partial<<<dim3(32, 8), 256, 0, stream>>>(x, psum, psq);
  bn_finalize<<<32, 256, 0, stream>>>(psum, psq, gamma, beta, scale, shift);
  build_wg<<<G4, 256, 0, stream>>>(W_hh, W_ih, b_ih, b_hh, Wg, bias);

  if (useWinB) {
    cvt_bf16<<<32768, 256, 0, stream>>>(W_in, WinB, (long)DIN * DIN);
    gemm1<1><<<dim3(64, 16), 256, 0, stream>>>(x, scale, shift, WinB, b_in, xs);
  } else {
    gemm1<0><<<dim3(64, 16), 256, 0, stream>>>(x, scale, shift, W_in, b_in, xs);
  }

  for (int t = 0; t < SEQ; ++t) {
    step_gemm<<<dim3(16, 16), 256, 0, stream>>>(hbuf, xs + (size_t)t * BATCH * 32, Wg, bias, gates);
    lstm_elt<<<4096, 256, 0, stream>>>(gates, cbuf, hbuf);
  }

  gemv_out<<<BATCH, 64, 0, stream>>>(hbuf, W_out, out);
}

// Round 2
// 4038.510 us; speedup vs baseline: 1.8578x; 1.8578x over previous
//
#include <hip/hip_runtime.h>

#define SEQ   256
#define DIN   8192
#define BATCH 2048
#define HID   512
#define G4    2048   // 4*HID
#define KG    544    // HID + 32

typedef __attribute__((ext_vector_type(8))) short short8;
typedef __attribute__((ext_vector_type(4))) float f32x4;

static __device__ __forceinline__ unsigned short f2bf(float f) {
  unsigned int u = __float_as_uint(f);
  return (unsigned short)((u + 0x7FFFu + ((u >> 16) & 1u)) >> 16);
}
static __device__ __forceinline__ float bf2f(unsigned short u) {
  return __uint_as_float(((unsigned int)u) << 16);
}
static __device__ __forceinline__ float sigmoidf_(float x) {
  return 1.f / (1.f + __expf(-x));
}
static __device__ __forceinline__ float tanhf_(float x) {
  return 1.f - 2.f / (__expf(2.f * x) + 1.f);
}

// ---------------- BatchNorm stats (two-stage) ----------------
__global__ __launch_bounds__(256) void bn_partial(const float* __restrict__ x,
                                                  float* __restrict__ psum,
                                                  float* __restrict__ psq) {
  int c = blockIdx.x * 256 + threadIdx.x;
  int r0 = blockIdx.y * 256;
  float s = 0.f, q = 0.f;
#pragma unroll 8
  for (int r = r0; r < r0 + 256; ++r) {
    float v = x[(size_t)r * DIN + c];
    s += v; q += v * v;
  }
  psum[blockIdx.y * DIN + c] = s;
  psq[blockIdx.y * DIN + c] = q;
}

__global__ __launch_bounds__(256) void bn_finalize(const float* __restrict__ psum,
                                                   const float* __restrict__ psq,
                                                   const float* __restrict__ gamma,
                                                   const float* __restrict__ beta,
                                                   float* __restrict__ scale,
                                                   float* __restrict__ shift) {
  int c = blockIdx.x * 256 + threadIdx.x;
  float s = 0.f, q = 0.f;
#pragma unroll
  for (int i = 0; i < 8; ++i) { s += psum[i * DIN + c]; q += psq[i * DIN + c]; }
  float mean = s * (1.f / BATCH);
  float var = q * (1.f / BATCH) - mean * mean;
  float sc = gamma[c] * rsqrtf(var + 1e-5f);
  scale[c] = sc;
  shift[c] = beta[c] - mean * sc;
}

// ---------------- prep: conversions ----------------
__global__ __launch_bounds__(256) void cvt_bf16(const float* __restrict__ in,
                                                unsigned short* __restrict__ out, long n) {
  long i = ((long)blockIdx.x * 256 + threadIdx.x) * 8;
  if (i >= n) return;
  float4 a = *(const float4*)(in + i);
  float4 b = *(const float4*)(in + i + 4);
  ushort4 lo, hi;
  lo.x = f2bf(a.x); lo.y = f2bf(a.y); lo.z = f2bf(a.z); lo.w = f2bf(a.w);
  hi.x = f2bf(b.x); hi.y = f2bf(b.y); hi.z = f2bf(b.z); hi.w = f2bf(b.w);
  *(ushort4*)(out + i) = lo;
  *(ushort4*)(out + i + 4) = hi;
}

// Gate-interleaved fused weight: row g' = u*4 + gate  (orig g = gate*512 + u)
// Wg2[g'][k] : k<512 -> W_hh[g][k] ; k>=512 -> W_ih[g][k-512]. bias2[g'] = b_ih[g]+b_hh[g]
__global__ __launch_bounds__(256) void build_wg2(const float* __restrict__ W_hh,
                                                 const float* __restrict__ W_ih,
                                                 const float* __restrict__ b_ih,
                                                 const float* __restrict__ b_hh,
                                                 unsigned short* __restrict__ Wg2,
                                                 float* __restrict__ bias2) {
  int gp = blockIdx.x;                 // interleaved row
  int u = gp >> 2, gate = gp & 3;
  int g = gate * HID + u;              // original row
  for (int k = threadIdx.x; k < KG; k += 256) {
    float v = (k < HID) ? W_hh[(size_t)g * HID + k] : W_ih[(size_t)g * 32 + (k - HID)];
    Wg2[(size_t)gp * KG + k] = f2bf(v);
  }
  if (threadIdx.x == 0) bias2[gp] = b_ih[g] + b_hh[g];
}

// ---------------- GEMM1: C = norm(x) @ W_in^T + b_in  -> xs bf16 [T][B][32] ----------------
template<int BF16B>
__global__ __launch_bounds__(256) void gemm1(const float* __restrict__ x,
                                             const float* __restrict__ scale,
                                             const float* __restrict__ shift,
                                             const void* __restrict__ Bsrc,
                                             const float* __restrict__ b_in,
                                             unsigned short* __restrict__ xs) {
  __shared__ unsigned short As[128 * 40];
  __shared__ unsigned short Bs[128 * 40];
  const int tid = threadIdx.x;
  const int lane = tid & 63;
  const int wave = tid >> 6;
  const int wm = (wave >> 1) * 64, wn = (wave & 1) * 64;
  const int bn = blockIdx.x * 128, bm = blockIdx.y * 128;
  const int lr = lane & 15;
  const int kq = (lane >> 4) * 8;

  f32x4 acc[4][4] = {};

  for (int k0 = 0; k0 < DIN; k0 += 32) {
#pragma unroll
    for (int i = 0; i < 4; ++i) {
      int idx = tid + i * 256;
      int row = idx >> 3, c4 = (idx & 7) * 4;
      float4 v = *(const float4*)&x[(size_t)(bm + row) * DIN + k0 + c4];
      float4 sc = *(const float4*)&scale[k0 + c4];
      float4 sh = *(const float4*)&shift[k0 + c4];
      ushort4 o;
      o.x = f2bf(v.x * sc.x + sh.x);
      o.y = f2bf(v.y * sc.y + sh.y);
      o.z = f2bf(v.z * sc.z + sh.z);
      o.w = f2bf(v.w * sc.w + sh.w);
      *(ushort4*)&As[row * 40 + c4] = o;
    }
    if constexpr (BF16B) {
      const unsigned short* W = (const unsigned short*)Bsrc;
#pragma unroll
      for (int i = 0; i < 2; ++i) {
        int idx = tid + i * 256;
        int row = idx >> 2, cc = (idx & 3) * 8;
        *(int4*)&Bs[row * 40 + cc] = *(const int4*)&W[(size_t)(bn + row) * DIN + k0 + cc];
      }
    } else {
      const float* W = (const float*)Bsrc;
#pragma unroll
      for (int i = 0; i < 4; ++i) {
        int idx = tid + i * 256;
        int row = idx >> 3, c4 = (idx & 7) * 4;
        float4 v = *(const float4*)&W[(size_t)(bn + row) * DIN + k0 + c4];
        ushort4 o;
        o.x = f2bf(v.x); o.y = f2bf(v.y); o.z = f2bf(v.z); o.w = f2bf(v.w);
        *(ushort4*)&Bs[row * 40 + c4] = o;
      }
    }
    __syncthreads();
    short8 af[4], bfr[4];
#pragma unroll
    for (int i = 0; i < 4; ++i) af[i] = *(const short8*)&As[(wm + i * 16 + lr) * 40 + kq];
#pragma unroll
    for (int j = 0; j < 4; ++j) bfr[j] = *(const short8*)&Bs[(wn + j * 16 + lr) * 40 + kq];
#pragma unroll
    for (int i = 0; i < 4; ++i)
#pragma unroll
      for (int j = 0; j < 4; ++j)
        acc[i][j] = __builtin_amdgcn_mfma_f32_16x16x32_bf16(af[i], bfr[j], acc[i][j], 0, 0, 0);
    __syncthreads();
  }
#pragma unroll
  for (int i = 0; i < 4; ++i)
#pragma unroll
    for (int j = 0; j < 4; ++j)
#pragma unroll
      for (int r = 0; r < 4; ++r) {
        int row = bm + wm + i * 16 + (lane >> 4) * 4 + r;
        int col = bn + wn + j * 16 + lr;
        float val = acc[i][j][r] + b_in[col];
        xs[((size_t)(col >> 5) * BATCH + row) * 32 + (col & 31)] = f2bf(val);
      }
}

// ---------------- fused step: gates GEMM + LSTM cell epilogue ----------------
// 64x64 tile, gate-interleaved N axis. hin read-only, hout separate (double buffer).
__global__ __launch_bounds__(256) void step_fused(const unsigned short* __restrict__ hin,
                                                  const unsigned short* __restrict__ xst,
                                                  const unsigned short* __restrict__ Wg2,
                                                  const float* __restrict__ bias2,
                                                  float* __restrict__ c,
                                                  unsigned short* __restrict__ hout) {
  __shared__ unsigned short As[64 * 40];
  __shared__ unsigned short Bs[64 * 40];
  __shared__ float gt[64 * 68];
  const int tid = threadIdx.x;
  const int lane = tid & 63;
  const int wave = tid >> 6;
  const int wm = (wave >> 1) * 32, wn = (wave & 1) * 32;
  // XCD-aware bijective swizzle: 1024 blocks, 8 XCDs, 128 blocks/XCD contiguous
  const int orig = blockIdx.x;
  const int wgid = (orig & 7) * 128 + (orig >> 3);
  const int bx = wgid & 31, by = wgid >> 5;
  const int bm = by * 64, bn = bx * 64;
  const int lr = lane & 15;
  const int kq = (lane >> 4) * 8;
  const int srow = tid >> 2, scc = (tid & 3) * 8;

  f32x4 acc[2][2] = {};

  for (int kt = 0; kt < 17; ++kt) {
    const int k0 = kt * 32;
    int4 av, bv;
    if (kt < 16) av = *(const int4*)&hin[(size_t)(bm + srow) * HID + k0 + scc];
    else         av = *(const int4*)&xst[(size_t)(bm + srow) * 32 + scc];
    bv = *(const int4*)&Wg2[(size_t)(bn + srow) * KG + k0 + scc];
    *(int4*)&As[srow * 40 + scc] = av;
    *(int4*)&Bs[srow * 40 + scc] = bv;
    __syncthreads();
    short8 af[2], bfr[2];
#pragma unroll
    for (int i = 0; i < 2; ++i) af[i] = *(const short8*)&As[(wm + i * 16 + lr) * 40 + kq];
#pragma unroll
    for (int j = 0; j < 2; ++j) bfr[j] = *(const short8*)&Bs[(wn + j * 16 + lr) * 40 + kq];
#pragma unroll
    for (int i = 0; i < 2; ++i)
#pragma unroll
      for (int j = 0; j < 2; ++j)
        acc[i][j] = __builtin_amdgcn_mfma_f32_16x16x32_bf16(af[i], bfr[j], acc[i][j], 0, 0, 0);
    __syncthreads();
  }

  // gates -> LDS (with bias)
#pragma unroll
  for (int i = 0; i < 2; ++i)
#pragma unroll
    for (int j = 0; j < 2; ++j) {
      int colb = wn + j * 16 + lr;
      float bsum = bias2[bn + colb];
#pragma unroll
      for (int r = 0; r < 4; ++r) {
        int row = wm + i * 16 + (lane >> 4) * 4 + r;
        gt[row * 68 + colb] = acc[i][j][r] + bsum;
      }
    }
  __syncthreads();

  // cell update: thread handles 4 consecutive u for one batch row
  {
    const int row = tid >> 2, q = tid & 3;
    const int b = bm + row;
    const int u0 = (bn >> 2) + q * 4;          // bx*16 + q*4
    const float* gtr = &gt[row * 68 + q * 16]; // 16 floats: [u][gate] for 4 u
    const size_t cidx = (size_t)b * HID + u0;
    float4 cold = *(const float4*)&c[cidx];
    float cn[4];
    ushort4 hv;
    const float* co = &cold.x;
#pragma unroll
    for (int k = 0; k < 4; ++k) {
      float iv = sigmoidf_(gtr[k * 4 + 0]);
      float fv = sigmoidf_(gtr[k * 4 + 1]);
      float gv = tanhf_(gtr[k * 4 + 2]);
      float ov = sigmoidf_(gtr[k * 4 + 3]);
      float ccn = fv * co[k] + iv * gv;
      cn[k] = ccn;
      ((unsigned short*)&hv)[k] = f2bf(ov * tanhf_(ccn));
    }
    float4 cw; cw.x = cn[0]; cw.y = cn[1]; cw.z = cn[2]; cw.w = cn[3];
    *(float4*)&c[cidx] = cw;
    *(ushort4*)&hout[cidx] = hv;
  }
}

// ---------------- final GEMV: out[b] = h[b,:] . W_out ----------------
__global__ __launch_bounds__(64) void gemv_out(const unsigned short* __restrict__ h,
                                               const float* __restrict__ Wout,
                                               float* __restrict__ out) {
  int b = blockIdx.x;
  int lane = threadIdx.x;
  float s = 0.f;
#pragma unroll
  for (int i = 0; i < 8; ++i) {
    int u = lane + i * 64;
    s += bf2f(h[(size_t)b * HID + u]) * Wout[u];
  }
#pragma unroll
  for (int off = 32; off > 0; off >>= 1) s += __shfl_down(s, off);
  if (lane == 0) out[b] = s;
}

// ---------------- host ----------------
extern "C" void kernel_launch(void* const* d_in, const int* in_sizes, int n_in,
                              void* d_out, int out_size, void* d_ws, size_t ws_size,
                              hipStream_t stream) {
  const float* x     = (const float*)d_in[0];
  const float* gamma = (const float*)d_in[1];
  const float* beta  = (const float*)d_in[2];
  const float* W_in  = (const float*)d_in[3];
  const float* b_in  = (const float*)d_in[4];
  const float* W_ih  = (const float*)d_in[5];
  const float* W_hh  = (const float*)d_in[6];
  const float* b_ih  = (const float*)d_in[7];
  const float* b_hh  = (const float*)d_in[8];
  const float* W_out = (const float*)d_in[9];
  float* out = (float*)d_out;

  // workspace layout (bytes):
  //   0         scale[8192] f32                32768
  //   32768     shift[8192] f32                32768
  //   65536     bias2[2048] f32                 8192
  //   73728     Wg2 bf16 [2048][544]         2228224
  //   2301952   h0  bf16 [2048][512]         2097152
  //   4399104   h1  bf16 [2048][512]         2097152
  //   6496256   c   f32  [2048][512]         4194304
  //   10690560  xs  bf16 [256][2048][32]    33554432
  //   44244992  BN partials (2 x 8x8192 f32)  524288
  //   44769280  WinB bf16 [8192][8192]     134217728 (optional)
  char* ws = (char*)d_ws;
  float* scale = (float*)(ws + 0);
  float* shift = (float*)(ws + 32768);
  float* bias2 = (float*)(ws + 65536);
  unsigned short* Wg2 = (unsigned short*)(ws + 73728);
  unsigned short* h0  = (unsigned short*)(ws + 2301952);
  unsigned short* h1  = (unsigned short*)(ws + 4399104);
  float* cbuf = (float*)(ws + 6496256);
  unsigned short* xs  = (unsigned short*)(ws + 10690560);
  float* psum = (float*)(ws + 44244992);
  float* psq  = psum + 8 * DIN;
  unsigned short* WinB = (unsigned short*)(ws + 44769280);
  const bool useWinB = ws_size >= (44769280ull + 134217728ull);

  hipMemsetAsync(h0, 0, (size_t)BATCH * HID * 2, stream);
  hipMemsetAsync(cbuf, 0, (size_t)BATCH * HID * 4, stream);

  bn_partial<<<dim3(32, 8), 256, 0, stream>>>(x, psum, psq);
  bn_finalize<<<32, 256, 0, stream>>>(psum, psq, gamma, beta, scale, shift);
  build_wg2<<<G4, 256, 0, stream>>>(W_hh, W_ih, b_ih, b_hh, Wg2, bias2);

  if (useWinB) {
    cvt_bf16<<<32768, 256, 0, stream>>>(W_in, WinB, (long)DIN * DIN);
    gemm1<1><<<dim3(64, 16), 256, 0, stream>>>(x, scale, shift, WinB, b_in, xs);
  } else {
    gemm1<0><<<dim3(64, 16), 256, 0, stream>>>(x, scale, shift, W_in, b_in, xs);
  }

  for (int t = 0; t < SEQ; ++t) {
    const unsigned short* hin = (t & 1) ? h1 : h0;
    unsigned short* hout      = (t & 1) ? h0 : h1;
    step_fused<<<1024, 256, 0, stream>>>(hin, xs + (size_t)t * BATCH * 32, Wg2, bias2, cbuf, hout);
  }
  // after 256 steps (even), final h is in h0
  gemv_out<<<BATCH, 64, 0, stream>>>(h0, W_out, out);
}